// Round 1
// baseline (1390.989 us; speedup 1.0000x reference)
//
#include <hip/hip_runtime.h>
#include <hip/hip_bf16.h>
#include <cstdint>
#include <cstddef>

typedef __bf16 bf16_t;
typedef bf16_t bf16x8 __attribute__((ext_vector_type(8)));
typedef bf16_t bf16x4 __attribute__((ext_vector_type(4)));
typedef float f32x4 __attribute__((ext_vector_type(4)));

#define NEG_BIG (-1e30f)

// ---------------- fp32 -> bf16 convert with K padding ----------------
__global__ __launch_bounds__(256) void convert_pad(const float* __restrict__ src,
                                                   bf16_t* __restrict__ dst,
                                                   int incols, int outcols) {
    const int row = blockIdx.x;
    const float* s = src + (size_t)row * incols;
    bf16_t* d = dst + (size_t)row * outcols;
    const int n4 = outcols >> 2;
    for (int c = threadIdx.x; c < n4; c += blockDim.x) {
        const int col = c << 2;
        float4 v;
        if (col < incols) v = *(const float4*)(s + col);   // incols % 4 == 0
        else              v = make_float4(0.f, 0.f, 0.f, 0.f);
        bf16x4 o;
        o[0] = (bf16_t)v.x; o[1] = (bf16_t)v.y; o[2] = (bf16_t)v.z; o[3] = (bf16_t)v.w;
        *(bf16x4*)(d + col) = o;
    }
}

// ---------------- bf16 GEMM: Z = A[M,K] @ W[N,K]^T + bias, Z bf16 ----------------
#define BM 128
#define BN 128
#define BK 32

__global__ __launch_bounds__(256) void gemm_bt(const bf16_t* __restrict__ A,
                                               const bf16_t* __restrict__ W,
                                               const float* __restrict__ bias,
                                               bf16_t* __restrict__ Z,
                                               int K, int N) {
    __shared__ __align__(16) bf16_t As[BM * BK];
    __shared__ __align__(16) bf16_t Bs[BN * BK];
    const int tid  = threadIdx.x;
    const int wid  = tid >> 6;
    const int lane = tid & 63;

    // XCD-chunked bijective swizzle: consecutive logical M-rows stay on one XCD,
    // so the 8 blocks sharing an A-panel hit the same L2. gridDim.x % 8 == 0.
    const int bid = (int)blockIdx.x;
    const int cpx = (int)gridDim.x >> 3;
    const int swz = (bid & 7) * cpx + (bid >> 3);
    const int nbn = N >> 7;                 // N / BN
    const int n0 = (swz % nbn) * BN;
    const int m0 = (swz / nbn) * BM;

    const int wm = (wid >> 1) * 64;   // wave row offset within tile
    const int wn = (wid & 1) * 64;    // wave col offset within tile

    f32x4 acc[4][4] = {};

    // staging: 8 instrs per tile; instr idx = wid*2+t covers rows [idx*16, idx*16+16)
    const int srow0 = wid * 32 + (lane >> 2);     // t=0 row; t=1 adds 16
    const int scol  = (lane & 3) * 8;             // element offset (8 bf16 = 16B)

    const bf16_t* Aptr0 = A + (size_t)(m0 + srow0) * K + scol;
    const bf16_t* Aptr1 = A + (size_t)(m0 + srow0 + 16) * K + scol;
    const bf16_t* Wptr0 = W + (size_t)(n0 + srow0) * K + scol;
    const bf16_t* Wptr1 = W + (size_t)(n0 + srow0 + 16) * K + scol;

    bf16_t* AsB0 = As + (wid * 2 + 0) * 512;   // wave-uniform LDS bases
    bf16_t* AsB1 = As + (wid * 2 + 1) * 512;
    bf16_t* BsB0 = Bs + (wid * 2 + 0) * 512;
    bf16_t* BsB1 = Bs + (wid * 2 + 1) * 512;

    for (int k0 = 0; k0 < K; k0 += BK) {
        __syncthreads();
        __builtin_amdgcn_global_load_lds((const __attribute__((address_space(1))) void*)(Aptr0 + k0),
                                         (__attribute__((address_space(3))) void*)AsB0, 16, 0, 0);
        __builtin_amdgcn_global_load_lds((const __attribute__((address_space(1))) void*)(Aptr1 + k0),
                                         (__attribute__((address_space(3))) void*)AsB1, 16, 0, 0);
        __builtin_amdgcn_global_load_lds((const __attribute__((address_space(1))) void*)(Wptr0 + k0),
                                         (__attribute__((address_space(3))) void*)BsB0, 16, 0, 0);
        __builtin_amdgcn_global_load_lds((const __attribute__((address_space(1))) void*)(Wptr1 + k0),
                                         (__attribute__((address_space(3))) void*)BsB1, 16, 0, 0);
        __syncthreads();

        const int arow = wm + (lane & 15);
        const int brow = wn + (lane & 15);
        const int koff = (lane >> 4) * 8;
        bf16x8 af[4], bfr[4];
        #pragma unroll
        for (int i = 0; i < 4; ++i)
            af[i] = *(const bf16x8*)(As + (arow + i * 16) * BK + koff);
        #pragma unroll
        for (int j = 0; j < 4; ++j)
            bfr[j] = *(const bf16x8*)(Bs + (brow + j * 16) * BK + koff);
        #pragma unroll
        for (int i = 0; i < 4; ++i)
            #pragma unroll
            for (int j = 0; j < 4; ++j)
                acc[i][j] = __builtin_amdgcn_mfma_f32_16x16x32_bf16(af[i], bfr[j], acc[i][j], 0, 0, 0);
    }

    // epilogue: C/D layout col=lane&15, row=(lane>>4)*4+r
    const int cq = lane >> 4;
    const int cl = lane & 15;
    #pragma unroll
    for (int j = 0; j < 4; ++j) {
        const int col = n0 + wn + j * 16 + cl;
        const float bj = bias[col];
        #pragma unroll
        for (int i = 0; i < 4; ++i) {
            const int row = m0 + wm + i * 16 + cq * 4;
            #pragma unroll
            for (int r = 0; r < 4; ++r)
                Z[(size_t)(row + r) * N + col] = (bf16_t)(acc[i][j][r] + bj);
        }
    }
}

// ---------------- mixed activation + dropout-mask + mask passthrough ----------------
// One WAVE per row (64 lanes x 16 cols), 4 rows per 256-thread block.
// Single pass: no max subtraction (|z| <= ~10 for this net => exp safe in fp32),
// so softmax needs only a sum; all reductions are wave shuffles, no barriers/LDS.
__global__ __launch_bounds__(256) void act_kernel(const bf16_t* __restrict__ Z,
                                                  const float* __restrict__ mask,
                                                  const int* __restrict__ tids,
                                                  bf16_t* __restrict__ H,
                                                  float* __restrict__ mask_out) {
    const int wid  = threadIdx.x >> 6;
    const int lane = threadIdx.x & 63;
    const int row  = (int)blockIdx.x * 4 + wid;
    const size_t rb = (size_t)row * 1024;

    float z[16], e[16];
    int   ty[16];
    float4 mk[4];
    float s3 = 0.f, s4 = 0.f;

    #pragma unroll
    for (int q = 0; q < 4; ++q) {
        const int c0 = (q * 64 + lane) * 4;
        const bf16x4 z4 = *(const bf16x4*)(Z + rb + c0);
        const int4   t4 = *(const int4*)(tids + c0);
        mk[q] = *(const float4*)(mask + rb + c0);
        const int tt[4] = {t4.x, t4.y, t4.z, t4.w};
        #pragma unroll
        for (int j = 0; j < 4; ++j) {
            const int i = q * 4 + j;
            const float zz = (float)z4[j];
            z[i] = zz; ty[i] = tt[j];
            const float az = fabsf(zz);
            // one exp per element, argument selected by type:
            // tanh -> -2|z|, sigmoid -> -|z|, smax3 -> z, smin4 -> -z, else 0
            const float arg = (tt[j] == 1) ? -2.f * az
                            : (tt[j] == 2) ? -az
                            : (tt[j] == 3) ? zz
                            : (tt[j] == 4) ? -zz : 0.f;
            const float ee = __expf(arg);
            e[i] = ee;
            s3 += (tt[j] == 3) ? ee : 0.f;
            s4 += (tt[j] == 4) ? ee : 0.f;
        }
    }
    #pragma unroll
    for (int off = 32; off > 0; off >>= 1) {
        s3 += __shfl_xor(s3, off);
        s4 += __shfl_xor(s4, off);
    }
    const float inv3 = 1.f / s3;   // inf only if no tid==3 col: never selected then
    const float inv4 = 1.f / s4;

    #pragma unroll
    for (int q = 0; q < 4; ++q) {
        const int c0 = (q * 64 + lane) * 4;
        const float mm[4] = {mk[q].x, mk[q].y, mk[q].z, mk[q].w};
        bf16x4 h4;
        #pragma unroll
        for (int j = 0; j < 4; ++j) {
            const int i = q * 4 + j;
            const float zz = z[i], ee = e[i];
            const int tt = ty[i];
            const float r1pe = __builtin_amdgcn_rcpf(1.f + ee);
            const float tha = (1.f - ee) * r1pe;               // tanh(|z|) when tt==1
            const float tnh = (zz >= 0.f) ? tha : -tha;
            const float sg  = ((zz >= 0.f) ? 1.f : ee) * r1pe; // sigmoid when tt==2
            const float gel = 0.5f * zz * (1.f + erff(zz * 0.70710678f));
            const float a = (tt == 0) ? fmaxf(zz, 0.f)
                          : (tt == 1) ? tnh
                          : (tt == 2) ? sg
                          : (tt == 3) ? ee * inv3
                          : (tt == 4) ? ee * inv4
                          : (tt == 5) ? gel
                          : fmaxf(zz, 0.01f * zz);             // lrelu
            h4[j] = (bf16_t)(a * mm[j] * 2.0f);                // KEEP_SCALE = 2
        }
        *(bf16x4*)(H + rb + c0) = h4;
        *(float4*)(mask_out + rb + c0) = mk[q];
    }
}

// ---------------- layer-3 act + final GEMV + log_softmax, fused ----------------
// h never touches HBM: stays in fp32 registers; W3 staged fp32 in LDS (40 KB).
// 2048 blocks x 16 rows (4 waves x 4 rows each).
__global__ __launch_bounds__(256) void act_final(const bf16_t* __restrict__ Z,
                                                 const float* __restrict__ mask,
                                                 const int* __restrict__ tids,
                                                 const float* __restrict__ W3,
                                                 const float* __restrict__ b3,
                                                 float* __restrict__ mask_out,
                                                 float* __restrict__ out) {
    __shared__ float Ws[10 * 1024];   // 40 KB fp32 -> 4 blocks/CU
    for (int i = threadIdx.x; i < 10240; i += 256) Ws[i] = W3[i];
    __syncthreads();

    const int wid  = threadIdx.x >> 6;
    const int lane = threadIdx.x & 63;

    // type ids are row-independent: load once per wave
    int ty[16];
    #pragma unroll
    for (int q = 0; q < 4; ++q) {
        const int4 t4 = *(const int4*)(tids + (q * 64 + lane) * 4);
        ty[q * 4 + 0] = t4.x; ty[q * 4 + 1] = t4.y;
        ty[q * 4 + 2] = t4.z; ty[q * 4 + 3] = t4.w;
    }

    #pragma unroll 1
    for (int rr = 0; rr < 4; ++rr) {
        const int row = (int)blockIdx.x * 16 + wid * 4 + rr;
        const size_t rb = (size_t)row * 1024;

        float z[16], e[16], h[16];
        float4 mk[4];
        float s3 = 0.f, s4 = 0.f;

        #pragma unroll
        for (int q = 0; q < 4; ++q) {
            const int c0 = (q * 64 + lane) * 4;
            const bf16x4 z4 = *(const bf16x4*)(Z + rb + c0);
            mk[q] = *(const float4*)(mask + rb + c0);
            #pragma unroll
            for (int j = 0; j < 4; ++j) {
                const int i = q * 4 + j;
                const float zz = (float)z4[j];
                z[i] = zz;
                const int tt = ty[i];
                const float az = fabsf(zz);
                const float arg = (tt == 1) ? -2.f * az
                                : (tt == 2) ? -az
                                : (tt == 3) ? zz
                                : (tt == 4) ? -zz : 0.f;
                const float ee = __expf(arg);
                e[i] = ee;
                s3 += (tt == 3) ? ee : 0.f;
                s4 += (tt == 4) ? ee : 0.f;
            }
        }
        #pragma unroll
        for (int off = 32; off > 0; off >>= 1) {
            s3 += __shfl_xor(s3, off);
            s4 += __shfl_xor(s4, off);
        }
        const float inv3 = 1.f / s3;
        const float inv4 = 1.f / s4;

        #pragma unroll
        for (int q = 0; q < 4; ++q) {
            const int c0 = (q * 64 + lane) * 4;
            const float mm[4] = {mk[q].x, mk[q].y, mk[q].z, mk[q].w};
            #pragma unroll
            for (int j = 0; j < 4; ++j) {
                const int i = q * 4 + j;
                const float zz = z[i], ee = e[i];
                const int tt = ty[i];
                const float r1pe = __builtin_amdgcn_rcpf(1.f + ee);
                const float tha = (1.f - ee) * r1pe;
                const float tnh = (zz >= 0.f) ? tha : -tha;
                const float sg  = ((zz >= 0.f) ? 1.f : ee) * r1pe;
                const float gel = 0.5f * zz * (1.f + erff(zz * 0.70710678f));
                const float a = (tt == 0) ? fmaxf(zz, 0.f)
                              : (tt == 1) ? tnh
                              : (tt == 2) ? sg
                              : (tt == 3) ? ee * inv3
                              : (tt == 4) ? ee * inv4
                              : (tt == 5) ? gel
                              : fmaxf(zz, 0.01f * zz);
                h[i] = a * mm[j] * 2.0f;
            }
            *(float4*)(mask_out + rb + c0) = mk[q];
        }

        // logits: 10 dot products against LDS-resident fp32 W3
        float acc[10];
        #pragma unroll
        for (int n = 0; n < 10; ++n) acc[n] = 0.f;
        #pragma unroll
        for (int q = 0; q < 4; ++q) {
            const int c0 = (q * 64 + lane) * 4;
            #pragma unroll
            for (int n = 0; n < 10; ++n) {
                const float4 w = *(const float4*)(Ws + n * 1024 + c0);
                acc[n] += h[q*4+0] * w.x + h[q*4+1] * w.y + h[q*4+2] * w.z + h[q*4+3] * w.w;
            }
        }
        #pragma unroll
        for (int n = 0; n < 10; ++n)
            #pragma unroll
            for (int off = 32; off > 0; off >>= 1)
                acc[n] += __shfl_xor(acc[n], off);

        if (lane == 0) {
            float lg[10]; float mx = -1e30f;
            #pragma unroll
            for (int n = 0; n < 10; ++n) { lg[n] = acc[n] + b3[n]; mx = fmaxf(mx, lg[n]); }
            float se = 0.f;
            #pragma unroll
            for (int n = 0; n < 10; ++n) se += __expf(lg[n] - mx);
            const float lse = logf(se) + mx;
            #pragma unroll
            for (int n = 0; n < 10; ++n) out[(size_t)row * 10 + n] = lg[n] - lse;
        }
    }
}

extern "C" void kernel_launch(void* const* d_in, const int* in_sizes, int n_in,
                              void* d_out, int out_size, void* d_ws, size_t ws_size,
                              hipStream_t stream) {
    (void)in_sizes; (void)n_in; (void)out_size; (void)ws_size;
    const float* x     = (const float*)d_in[0];
    const float* W0    = (const float*)d_in[1];
    const float* b0    = (const float*)d_in[2];
    const float* W1    = (const float*)d_in[3];
    const float* b1    = (const float*)d_in[4];
    const float* W2    = (const float*)d_in[5];
    const float* b2    = (const float*)d_in[6];
    const float* W3    = (const float*)d_in[7];
    const float* b3    = (const float*)d_in[8];
    const float* mask1 = (const float*)d_in[9];
    const float* mask2 = (const float*)d_in[10];
    const float* mask3 = (const float*)d_in[11];
    const int*   tids  = (const int*)d_in[12];

    float* out = (float*)d_out;
    float* mo1 = out + 327680;               // 32768*10
    float* mo2 = mo1 + 33554432;             // 32768*1024
    float* mo3 = mo2 + 33554432;

    char* ws = (char*)d_ws;
    bf16_t* xb  = (bf16_t*)ws;  ws += (size_t)32768 * 800 * 2;
    bf16_t* W0b = (bf16_t*)ws;  ws += (size_t)1024 * 800 * 2;
    bf16_t* W1b = (bf16_t*)ws;  ws += (size_t)1024 * 1024 * 2;
    bf16_t* W2b = (bf16_t*)ws;  ws += (size_t)1024 * 1024 * 2;
    bf16_t* Zb  = (bf16_t*)ws;  ws += (size_t)32768 * 1024 * 2;
    bf16_t* hb  = (bf16_t*)ws;  ws += (size_t)32768 * 1024 * 2;
    // total workspace: ~192 MiB

    convert_pad<<<32768, 256, 0, stream>>>(x,  xb,  784, 800);
    convert_pad<<<1024,  256, 0, stream>>>(W0, W0b, 784, 800);
    convert_pad<<<1024,  256, 0, stream>>>(W1, W1b, 1024, 1024);
    convert_pad<<<1024,  256, 0, stream>>>(W2, W2b, 1024, 1024);

    gemm_bt<<<2048, 256, 0, stream>>>(xb, W0b, b0, Zb, 800, 1024);
    act_kernel<<<8192, 256, 0, stream>>>(Zb, mask1, tids, hb, mo1);
    gemm_bt<<<2048, 256, 0, stream>>>(hb, W1b, b1, Zb, 1024, 1024);
    act_kernel<<<8192, 256, 0, stream>>>(Zb, mask2, tids + 1024, hb, mo2);
    gemm_bt<<<2048, 256, 0, stream>>>(hb, W2b, b2, Zb, 1024, 1024);
    act_final<<<2048, 256, 0, stream>>>(Zb, mask3, tids + 2048, W3, b3, mo3, out);
}

// Round 2
// 1203.250 us; speedup vs baseline: 1.1560x; 1.1560x over previous
//
#include <hip/hip_runtime.h>
#include <hip/hip_bf16.h>
#include <cstdint>
#include <cstddef>

typedef __bf16 bf16_t;
typedef bf16_t bf16x8 __attribute__((ext_vector_type(8)));
typedef bf16_t bf16x4 __attribute__((ext_vector_type(4)));
typedef float f32x4 __attribute__((ext_vector_type(4)));

#define NEG_BIG (-1e30f)

// ---------------- fp32 -> bf16 convert with K padding ----------------
__global__ __launch_bounds__(256) void convert_pad(const float* __restrict__ src,
                                                   bf16_t* __restrict__ dst,
                                                   int incols, int outcols) {
    const int row = blockIdx.x;
    const float* s = src + (size_t)row * incols;
    bf16_t* d = dst + (size_t)row * outcols;
    const int n4 = outcols >> 2;
    for (int c = threadIdx.x; c < n4; c += blockDim.x) {
        const int col = c << 2;
        float4 v;
        if (col < incols) v = *(const float4*)(s + col);   // incols % 4 == 0
        else              v = make_float4(0.f, 0.f, 0.f, 0.f);
        bf16x4 o;
        o[0] = (bf16_t)v.x; o[1] = (bf16_t)v.y; o[2] = (bf16_t)v.z; o[3] = (bf16_t)v.w;
        *(bf16x4*)(d + col) = o;
    }
}

// ---------------- bf16 GEMM: Z = A[M,K] @ W[N,K]^T + bias, Z bf16 ----------------
#define BM 128
#define BN 128
#define BK 32

__global__ __launch_bounds__(256) void gemm_bt(const bf16_t* __restrict__ A,
                                               const bf16_t* __restrict__ W,
                                               const float* __restrict__ bias,
                                               bf16_t* __restrict__ Z,
                                               int K, int N) {
    __shared__ __align__(16) bf16_t As[BM * BK];
    __shared__ __align__(16) bf16_t Bs[BN * BK];
    const int tid  = threadIdx.x;
    const int wid  = tid >> 6;
    const int lane = tid & 63;

    // XCD-chunked bijective swizzle: consecutive logical M-rows stay on one XCD,
    // so the 8 blocks sharing an A-panel hit the same L2. gridDim.x % 8 == 0.
    const int bid = (int)blockIdx.x;
    const int cpx = (int)gridDim.x >> 3;
    const int swz = (bid & 7) * cpx + (bid >> 3);
    const int nbn = N >> 7;                 // N / BN
    const int n0 = (swz % nbn) * BN;
    const int m0 = (swz / nbn) * BM;

    const int wm = (wid >> 1) * 64;   // wave row offset within tile
    const int wn = (wid & 1) * 64;    // wave col offset within tile

    f32x4 acc[4][4] = {};

    // staging: 8 instrs per tile; instr idx = wid*2+t covers rows [idx*16, idx*16+16)
    const int srow0 = wid * 32 + (lane >> 2);     // t=0 row; t=1 adds 16
    const int scol  = (lane & 3) * 8;             // element offset (8 bf16 = 16B)

    const bf16_t* Aptr0 = A + (size_t)(m0 + srow0) * K + scol;
    const bf16_t* Aptr1 = A + (size_t)(m0 + srow0 + 16) * K + scol;
    const bf16_t* Wptr0 = W + (size_t)(n0 + srow0) * K + scol;
    const bf16_t* Wptr1 = W + (size_t)(n0 + srow0 + 16) * K + scol;

    bf16_t* AsB0 = As + (wid * 2 + 0) * 512;   // wave-uniform LDS bases
    bf16_t* AsB1 = As + (wid * 2 + 1) * 512;
    bf16_t* BsB0 = Bs + (wid * 2 + 0) * 512;
    bf16_t* BsB1 = Bs + (wid * 2 + 1) * 512;

    for (int k0 = 0; k0 < K; k0 += BK) {
        __syncthreads();
        __builtin_amdgcn_global_load_lds((const __attribute__((address_space(1))) void*)(Aptr0 + k0),
                                         (__attribute__((address_space(3))) void*)AsB0, 16, 0, 0);
        __builtin_amdgcn_global_load_lds((const __attribute__((address_space(1))) void*)(Aptr1 + k0),
                                         (__attribute__((address_space(3))) void*)AsB1, 16, 0, 0);
        __builtin_amdgcn_global_load_lds((const __attribute__((address_space(1))) void*)(Wptr0 + k0),
                                         (__attribute__((address_space(3))) void*)BsB0, 16, 0, 0);
        __builtin_amdgcn_global_load_lds((const __attribute__((address_space(1))) void*)(Wptr1 + k0),
                                         (__attribute__((address_space(3))) void*)BsB1, 16, 0, 0);
        __syncthreads();

        const int arow = wm + (lane & 15);
        const int brow = wn + (lane & 15);
        const int koff = (lane >> 4) * 8;
        bf16x8 af[4], bfr[4];
        #pragma unroll
        for (int i = 0; i < 4; ++i)
            af[i] = *(const bf16x8*)(As + (arow + i * 16) * BK + koff);
        #pragma unroll
        for (int j = 0; j < 4; ++j)
            bfr[j] = *(const bf16x8*)(Bs + (brow + j * 16) * BK + koff);
        #pragma unroll
        for (int i = 0; i < 4; ++i)
            #pragma unroll
            for (int j = 0; j < 4; ++j)
                acc[i][j] = __builtin_amdgcn_mfma_f32_16x16x32_bf16(af[i], bfr[j], acc[i][j], 0, 0, 0);
    }

    // epilogue: C/D layout col=lane&15, row=(lane>>4)*4+r
    const int cq = lane >> 4;
    const int cl = lane & 15;
    #pragma unroll
    for (int j = 0; j < 4; ++j) {
        const int col = n0 + wn + j * 16 + cl;
        const float bj = bias[col];
        #pragma unroll
        for (int i = 0; i < 4; ++i) {
            const int row = m0 + wm + i * 16 + cq * 4;
            #pragma unroll
            for (int r = 0; r < 4; ++r)
                Z[(size_t)(row + r) * N + col] = (bf16_t)(acc[i][j][r] + bj);
        }
    }
}

// ---------------- mixed activation + dropout-mask + mask passthrough ----------------
// One WAVE per row (64 lanes x 16 cols), 4 rows per 256-thread block.
// Single pass: no max subtraction (|z| <= ~10 for this net => exp safe in fp32),
// so softmax needs only a sum; all reductions are wave shuffles, no barriers/LDS.
__global__ __launch_bounds__(256) void act_kernel(const bf16_t* __restrict__ Z,
                                                  const float* __restrict__ mask,
                                                  const int* __restrict__ tids,
                                                  bf16_t* __restrict__ H,
                                                  float* __restrict__ mask_out) {
    const int wid  = threadIdx.x >> 6;
    const int lane = threadIdx.x & 63;
    const int row  = (int)blockIdx.x * 4 + wid;
    const size_t rb = (size_t)row * 1024;

    float z[16], e[16];
    int   ty[16];
    float4 mk[4];
    float s3 = 0.f, s4 = 0.f;

    #pragma unroll
    for (int q = 0; q < 4; ++q) {
        const int c0 = (q * 64 + lane) * 4;
        const bf16x4 z4 = *(const bf16x4*)(Z + rb + c0);
        const int4   t4 = *(const int4*)(tids + c0);
        mk[q] = *(const float4*)(mask + rb + c0);
        const int tt[4] = {t4.x, t4.y, t4.z, t4.w};
        #pragma unroll
        for (int j = 0; j < 4; ++j) {
            const int i = q * 4 + j;
            const float zz = (float)z4[j];
            z[i] = zz; ty[i] = tt[j];
            const float az = fabsf(zz);
            // one exp per element, argument selected by type:
            // tanh -> -2|z|, sigmoid -> -|z|, smax3 -> z, smin4 -> -z, else 0
            const float arg = (tt[j] == 1) ? -2.f * az
                            : (tt[j] == 2) ? -az
                            : (tt[j] == 3) ? zz
                            : (tt[j] == 4) ? -zz : 0.f;
            const float ee = __expf(arg);
            e[i] = ee;
            s3 += (tt[j] == 3) ? ee : 0.f;
            s4 += (tt[j] == 4) ? ee : 0.f;
        }
    }
    #pragma unroll
    for (int off = 32; off > 0; off >>= 1) {
        s3 += __shfl_xor(s3, off);
        s4 += __shfl_xor(s4, off);
    }
    const float inv3 = 1.f / s3;   // inf only if no tid==3 col: never selected then
    const float inv4 = 1.f / s4;

    #pragma unroll
    for (int q = 0; q < 4; ++q) {
        const int c0 = (q * 64 + lane) * 4;
        const float mm[4] = {mk[q].x, mk[q].y, mk[q].z, mk[q].w};
        bf16x4 h4;
        #pragma unroll
        for (int j = 0; j < 4; ++j) {
            const int i = q * 4 + j;
            const float zz = z[i], ee = e[i];
            const int tt = ty[i];
            const float r1pe = __builtin_amdgcn_rcpf(1.f + ee);
            const float tha = (1.f - ee) * r1pe;               // tanh(|z|) when tt==1
            const float tnh = (zz >= 0.f) ? tha : -tha;
            const float sg  = ((zz >= 0.f) ? 1.f : ee) * r1pe; // sigmoid when tt==2
            const float gel = 0.5f * zz * (1.f + erff(zz * 0.70710678f));
            const float a = (tt == 0) ? fmaxf(zz, 0.f)
                          : (tt == 1) ? tnh
                          : (tt == 2) ? sg
                          : (tt == 3) ? ee * inv3
                          : (tt == 4) ? ee * inv4
                          : (tt == 5) ? gel
                          : fmaxf(zz, 0.01f * zz);             // lrelu
            h4[j] = (bf16_t)(a * mm[j] * 2.0f);                // KEEP_SCALE = 2
        }
        *(bf16x4*)(H + rb + c0) = h4;
        *(float4*)(mask_out + rb + c0) = mk[q];
    }
}

// ---------------- layer-3 act + final GEMV + log_softmax, fused ----------------
// One row per WAVE (like act_kernel), 4 waves/block, 8192 blocks.
// W3 staged as bf16 in 20 KB LDS (occupancy cap 8 blocks/CU); h stays in fp32 regs.
__global__ __launch_bounds__(256) void act_final(const bf16_t* __restrict__ Z,
                                                 const float* __restrict__ mask,
                                                 const int* __restrict__ tids,
                                                 const bf16_t* __restrict__ W3b,
                                                 const float* __restrict__ b3,
                                                 float* __restrict__ mask_out,
                                                 float* __restrict__ out) {
    __shared__ __align__(16) bf16_t Ws[10 * 1024];   // 20 KB bf16
    #pragma unroll
    for (int i = threadIdx.x * 8; i < 10240; i += 2048)
        *(bf16x8*)(Ws + i) = *(const bf16x8*)(W3b + i);
    __syncthreads();

    const int wid  = threadIdx.x >> 6;
    const int lane = threadIdx.x & 63;
    const int row  = (int)blockIdx.x * 4 + wid;
    const size_t rb = (size_t)row * 1024;

    float z[16], e[16];
    float4 mk[4];
    float s3 = 0.f, s4 = 0.f;

    // pass 1: load z, compute the one exp per element, accumulate softmax sums
    #pragma unroll
    for (int q = 0; q < 4; ++q) {
        const int c0 = (q * 64 + lane) * 4;
        const bf16x4 z4 = *(const bf16x4*)(Z + rb + c0);
        const int4   t4 = *(const int4*)(tids + c0);
        mk[q] = *(const float4*)(mask + rb + c0);
        const int tt[4] = {t4.x, t4.y, t4.z, t4.w};
        #pragma unroll
        for (int j = 0; j < 4; ++j) {
            const int i = q * 4 + j;
            const float zz = (float)z4[j];
            z[i] = zz;
            const float az = fabsf(zz);
            const float arg = (tt[j] == 1) ? -2.f * az
                            : (tt[j] == 2) ? -az
                            : (tt[j] == 3) ? zz
                            : (tt[j] == 4) ? -zz : 0.f;
            const float ee = __expf(arg);
            e[i] = ee;
            s3 += (tt[j] == 3) ? ee : 0.f;
            s4 += (tt[j] == 4) ? ee : 0.f;
        }
    }
    #pragma unroll
    for (int off = 32; off > 0; off >>= 1) {
        s3 += __shfl_xor(s3, off);
        s4 += __shfl_xor(s4, off);
    }
    const float inv3 = 1.f / s3;
    const float inv4 = 1.f / s4;

    // pass 2: activation -> h (fp32 regs), mask passthrough, 10 LDS dot products
    float acc[10];
    #pragma unroll
    for (int n = 0; n < 10; ++n) acc[n] = 0.f;

    #pragma unroll
    for (int q = 0; q < 4; ++q) {
        const int c0 = (q * 64 + lane) * 4;
        const int4 t4 = *(const int4*)(tids + c0);   // reload (L1-hot) to cut VGPR
        const int tt4[4] = {t4.x, t4.y, t4.z, t4.w};
        const float mm[4] = {mk[q].x, mk[q].y, mk[q].z, mk[q].w};
        float h[4];
        #pragma unroll
        for (int j = 0; j < 4; ++j) {
            const int i = q * 4 + j;
            const float zz = z[i], ee = e[i];
            const int tt = tt4[j];
            const float r1pe = __builtin_amdgcn_rcpf(1.f + ee);
            const float tha = (1.f - ee) * r1pe;
            const float tnh = (zz >= 0.f) ? tha : -tha;
            const float sg  = ((zz >= 0.f) ? 1.f : ee) * r1pe;
            const float gel = 0.5f * zz * (1.f + erff(zz * 0.70710678f));
            const float a = (tt == 0) ? fmaxf(zz, 0.f)
                          : (tt == 1) ? tnh
                          : (tt == 2) ? sg
                          : (tt == 3) ? ee * inv3
                          : (tt == 4) ? ee * inv4
                          : (tt == 5) ? gel
                          : fmaxf(zz, 0.01f * zz);
            h[j] = a * mm[j] * 2.0f;
        }
        *(float4*)(mask_out + rb + c0) = mk[q];
        #pragma unroll
        for (int n = 0; n < 10; ++n) {
            const bf16x4 w4 = *(const bf16x4*)(Ws + n * 1024 + c0);
            acc[n] += h[0] * (float)w4[0] + h[1] * (float)w4[1]
                    + h[2] * (float)w4[2] + h[3] * (float)w4[3];
        }
    }

    #pragma unroll
    for (int n = 0; n < 10; ++n)
        #pragma unroll
        for (int off = 32; off > 0; off >>= 1)
            acc[n] += __shfl_xor(acc[n], off);

    if (lane == 0) {
        float lg[10]; float mx = -1e30f;
        #pragma unroll
        for (int n = 0; n < 10; ++n) { lg[n] = acc[n] + b3[n]; mx = fmaxf(mx, lg[n]); }
        float se = 0.f;
        #pragma unroll
        for (int n = 0; n < 10; ++n) se += __expf(lg[n] - mx);
        const float lse = logf(se) + mx;
        #pragma unroll
        for (int n = 0; n < 10; ++n) out[(size_t)row * 10 + n] = lg[n] - lse;
    }
}

extern "C" void kernel_launch(void* const* d_in, const int* in_sizes, int n_in,
                              void* d_out, int out_size, void* d_ws, size_t ws_size,
                              hipStream_t stream) {
    (void)in_sizes; (void)n_in; (void)out_size; (void)ws_size;
    const float* x     = (const float*)d_in[0];
    const float* W0    = (const float*)d_in[1];
    const float* b0    = (const float*)d_in[2];
    const float* W1    = (const float*)d_in[3];
    const float* b1    = (const float*)d_in[4];
    const float* W2    = (const float*)d_in[5];
    const float* b2    = (const float*)d_in[6];
    const float* W3    = (const float*)d_in[7];
    const float* b3    = (const float*)d_in[8];
    const float* mask1 = (const float*)d_in[9];
    const float* mask2 = (const float*)d_in[10];
    const float* mask3 = (const float*)d_in[11];
    const int*   tids  = (const int*)d_in[12];

    float* out = (float*)d_out;
    float* mo1 = out + 327680;               // 32768*10
    float* mo2 = mo1 + 33554432;             // 32768*1024
    float* mo3 = mo2 + 33554432;

    char* ws = (char*)d_ws;
    bf16_t* xb  = (bf16_t*)ws;  ws += (size_t)32768 * 800 * 2;
    bf16_t* W0b = (bf16_t*)ws;  ws += (size_t)1024 * 800 * 2;
    bf16_t* W1b = (bf16_t*)ws;  ws += (size_t)1024 * 1024 * 2;
    bf16_t* W2b = (bf16_t*)ws;  ws += (size_t)1024 * 1024 * 2;
    bf16_t* W3b = (bf16_t*)ws;  ws += (size_t)16 * 1024 * 2;
    bf16_t* Zb  = (bf16_t*)ws;  ws += (size_t)32768 * 1024 * 2;
    bf16_t* hb  = (bf16_t*)ws;  ws += (size_t)32768 * 1024 * 2;
    // total workspace: ~192 MiB

    convert_pad<<<32768, 256, 0, stream>>>(x,  xb,  784, 800);
    convert_pad<<<1024,  256, 0, stream>>>(W0, W0b, 784, 800);
    convert_pad<<<1024,  256, 0, stream>>>(W1, W1b, 1024, 1024);
    convert_pad<<<1024,  256, 0, stream>>>(W2, W2b, 1024, 1024);
    convert_pad<<<10,    256, 0, stream>>>(W3, W3b, 1024, 1024);

    gemm_bt<<<2048, 256, 0, stream>>>(xb, W0b, b0, Zb, 800, 1024);
    act_kernel<<<8192, 256, 0, stream>>>(Zb, mask1, tids, hb, mo1);
    gemm_bt<<<2048, 256, 0, stream>>>(hb, W1b, b1, Zb, 1024, 1024);
    act_kernel<<<8192, 256, 0, stream>>>(Zb, mask2, tids + 1024, hb, mo2);
    gemm_bt<<<2048, 256, 0, stream>>>(hb, W2b, b2, Zb, 1024, 1024);
    act_final<<<8192, 256, 0, stream>>>(Zb, mask3, tids + 2048, W3b, b3, mo3, out);
}

// Round 3
// 1130.760 us; speedup vs baseline: 1.2301x; 1.0641x over previous
//
#include <hip/hip_runtime.h>
#include <hip/hip_bf16.h>
#include <cstdint>
#include <cstddef>

typedef __bf16 bf16_t;
typedef bf16_t bf16x8 __attribute__((ext_vector_type(8)));
typedef bf16_t bf16x4 __attribute__((ext_vector_type(4)));
typedef float f32x4 __attribute__((ext_vector_type(4)));

#define NEG_BIG (-1e30f)

// ---------------- fp32 -> bf16 convert with K padding ----------------
__global__ __launch_bounds__(256) void convert_pad(const float* __restrict__ src,
                                                   bf16_t* __restrict__ dst,
                                                   int incols, int outcols) {
    const int row = blockIdx.x;
    const float* s = src + (size_t)row * incols;
    bf16_t* d = dst + (size_t)row * outcols;
    const int n4 = outcols >> 2;
    for (int c = threadIdx.x; c < n4; c += blockDim.x) {
        const int col = c << 2;
        float4 v;
        if (col < incols) v = *(const float4*)(s + col);   // incols % 4 == 0
        else              v = make_float4(0.f, 0.f, 0.f, 0.f);
        bf16x4 o;
        o[0] = (bf16_t)v.x; o[1] = (bf16_t)v.y; o[2] = (bf16_t)v.z; o[3] = (bf16_t)v.w;
        *(bf16x4*)(d + col) = o;
    }
}

// ---------------- bf16 GEMM: Z = A[M,K] @ W[N,K]^T + bias, Z bf16 ----------------
// BK=64: half the barrier drains of BK=32. LDS rows are 128 B (worst-case bank
// layout), so T2 swizzle: linear LDS dest (required by global_load_lds) +
// inverse-permuted GLOBAL source col-block + XOR-swizzled ds_read address.
// LDS[r, cblk] holds global colblk (cblk ^ (r&7)); read q via cblk = q ^ (r&7).
#define BM 128
#define BN 128
#define BK 64

__global__ __launch_bounds__(256) void gemm_bt(const bf16_t* __restrict__ A,
                                               const bf16_t* __restrict__ W,
                                               const float* __restrict__ bias,
                                               bf16_t* __restrict__ Z,
                                               int K, int N) {
    __shared__ __align__(16) bf16_t As[BM * BK];   // 16 KB
    __shared__ __align__(16) bf16_t Bs[BN * BK];   // 16 KB
    const int tid  = threadIdx.x;
    const int wid  = tid >> 6;
    const int lane = tid & 63;

    // XCD-chunked bijective swizzle (gridDim.x % 8 == 0)
    const int bid = (int)blockIdx.x;
    const int cpx = (int)gridDim.x >> 3;
    const int swz = (bid & 7) * cpx + (bid >> 3);
    const int nbn = N >> 7;                 // N / BN
    const int n0 = (swz % nbn) * BN;
    const int m0 = (swz / nbn) * BM;

    const int wm = (wid >> 1) * 64;   // wave row offset within tile
    const int wn = (wid & 1) * 64;    // wave col offset within tile

    f32x4 acc[4][4] = {};

    // staging: 16 chunks of 1 KB per array; wave w owns chunks w*4+t (t=0..3).
    // chunk c covers rows [c*8, c*8+8); lane l -> row c*8 + (l>>3), LDS colblk (l&7).
    // source colblk is (l&7) ^ ((l>>3)&7)  [inverse of the read-side XOR].
    const int srow = wid * 32 + (lane >> 3);
    const int scol = (((lane & 7) ^ ((lane >> 3) & 7)) * 8);
    const bf16_t* Ab = A + (size_t)(m0 + srow) * K + scol;
    const bf16_t* Wb = W + (size_t)(n0 + srow) * K + scol;
    bf16_t* AsW = As + wid * 2048;   // wave-uniform LDS bases (4 chunks x 512)
    bf16_t* BsW = Bs + wid * 2048;
    const size_t rstep = (size_t)8 * K;   // 8 rows per chunk

    for (int k0 = 0; k0 < K; k0 += BK) {
        __syncthreads();
        #pragma unroll
        for (int t = 0; t < 4; ++t)
            __builtin_amdgcn_global_load_lds(
                (const __attribute__((address_space(1))) void*)(Ab + k0 + t * rstep),
                (__attribute__((address_space(3))) void*)(AsW + t * 512), 16, 0, 0);
        #pragma unroll
        for (int t = 0; t < 4; ++t)
            __builtin_amdgcn_global_load_lds(
                (const __attribute__((address_space(1))) void*)(Wb + k0 + t * rstep),
                (__attribute__((address_space(3))) void*)(BsW + t * 512), 16, 0, 0);
        __syncthreads();

        const int arow = wm + (lane & 15);
        const int brow = wn + (lane & 15);
        const int qb   = (lane >> 4) * 16;          // byte offset of k-quarter
        const int rxa  = (arow & 7) << 4;           // read-side XOR
        const int rxb  = (brow & 7) << 4;
        const char* Ac = (const char*)As;
        const char* Bc = (const char*)Bs;

        #pragma unroll
        for (int kh = 0; kh < 2; ++kh) {
            bf16x8 af[4], bfr[4];
            #pragma unroll
            for (int i = 0; i < 4; ++i)
                af[i] = *(const bf16x8*)(Ac + ((((arow + i * 16) << 7) + qb + kh * 64) ^ rxa));
            #pragma unroll
            for (int j = 0; j < 4; ++j)
                bfr[j] = *(const bf16x8*)(Bc + ((((brow + j * 16) << 7) + qb + kh * 64) ^ rxb));
            #pragma unroll
            for (int i = 0; i < 4; ++i)
                #pragma unroll
                for (int j = 0; j < 4; ++j)
                    acc[i][j] = __builtin_amdgcn_mfma_f32_16x16x32_bf16(af[i], bfr[j], acc[i][j], 0, 0, 0);
        }
    }

    // epilogue: C/D layout col=lane&15, row=(lane>>4)*4+r
    const int cq = lane >> 4;
    const int cl = lane & 15;
    #pragma unroll
    for (int j = 0; j < 4; ++j) {
        const int col = n0 + wn + j * 16 + cl;
        const float bj = bias[col];
        #pragma unroll
        for (int i = 0; i < 4; ++i) {
            const int row = m0 + wm + i * 16 + cq * 4;
            #pragma unroll
            for (int r = 0; r < 4; ++r)
                Z[(size_t)(row + r) * N + col] = (bf16_t)(acc[i][j][r] + bj);
        }
    }
}

// ---------------- mixed activation + dropout-mask + mask passthrough ----------------
// One WAVE per row (64 lanes x 8 cols x 2). Single compute pass: activation is fully
// evaluated BEFORE the softmax-sum reduction (softmax elems carry exp; only the
// 1/sum scale is deferred). Type kept as two 16-bit masks (2 VGPRs, not 16).
__global__ __launch_bounds__(256) void act_kernel(const bf16_t* __restrict__ Z,
                                                  const float* __restrict__ mask,
                                                  const int* __restrict__ tids,
                                                  bf16_t* __restrict__ H,
                                                  float* __restrict__ mask_out) {
    const int wid  = threadIdx.x >> 6;
    const int lane = threadIdx.x & 63;
    const int row  = (int)blockIdx.x * 4 + wid;
    const size_t rb = (size_t)row * 1024;

    float p[16], mk[16];
    uint32_t m3 = 0, m4 = 0;
    float s3 = 0.f, s4 = 0.f;

    #pragma unroll
    for (int q = 0; q < 2; ++q) {
        const int c0 = (q * 64 + lane) * 8;
        const bf16x8 z8 = *(const bf16x8*)(Z + rb + c0);
        const int4   ta = *(const int4*)(tids + c0);
        const int4   tb = *(const int4*)(tids + c0 + 4);
        const float4 ma = *(const float4*)(mask + rb + c0);
        const float4 mb = *(const float4*)(mask + rb + c0 + 4);
        const int   tt8[8] = {ta.x, ta.y, ta.z, ta.w, tb.x, tb.y, tb.z, tb.w};
        const float mm8[8] = {ma.x, ma.y, ma.z, ma.w, mb.x, mb.y, mb.z, mb.w};
        #pragma unroll
        for (int j = 0; j < 8; ++j) {
            const int i = q * 8 + j;
            const float zz = (float)z8[j];
            const int tt = tt8[j];
            mk[i] = mm8[j];
            const float az = fabsf(zz);
            const float arg = (tt == 1) ? -2.f * az
                            : (tt == 2) ? -az
                            : (tt == 3) ? zz
                            : (tt == 4) ? -zz : 0.f;
            const float ee = __expf(arg);
            const float r1pe = __builtin_amdgcn_rcpf(1.f + ee);
            const float tha = (1.f - ee) * r1pe;               // tanh(|z|)
            const float tnh = (zz >= 0.f) ? tha : -tha;
            const float sg  = ((zz >= 0.f) ? 1.f : ee) * r1pe; // sigmoid
            const float gel = 0.5f * zz * (1.f + erff(zz * 0.70710678f));
            const float pre = (tt == 0) ? fmaxf(zz, 0.f)
                            : (tt == 1) ? tnh
                            : (tt == 2) ? sg
                            : (tt == 3) ? ee
                            : (tt == 4) ? ee
                            : (tt == 5) ? gel
                            : fmaxf(zz, 0.01f * zz);           // lrelu
            p[i] = pre;
            m3 |= (uint32_t)(tt == 3) << i;
            m4 |= (uint32_t)(tt == 4) << i;
            s3 += (tt == 3) ? ee : 0.f;
            s4 += (tt == 4) ? ee : 0.f;
        }
        *(float4*)(mask_out + rb + c0)     = ma;
        *(float4*)(mask_out + rb + c0 + 4) = mb;
    }
    #pragma unroll
    for (int off = 32; off > 0; off >>= 1) {
        s3 += __shfl_xor(s3, off);
        s4 += __shfl_xor(s4, off);
    }
    const float inv3 = 1.f / s3;   // inf only if no tid==3 col: never selected then
    const float inv4 = 1.f / s4;

    #pragma unroll
    for (int q = 0; q < 2; ++q) {
        const int c0 = (q * 64 + lane) * 8;
        bf16x8 h8;
        #pragma unroll
        for (int j = 0; j < 8; ++j) {
            const int i = q * 8 + j;
            const float sc = ((m3 >> i) & 1) ? inv3 : ((m4 >> i) & 1) ? inv4 : 1.f;
            h8[j] = (bf16_t)(p[i] * sc * mk[i] * 2.0f);        // KEEP_SCALE = 2
        }
        *(bf16x8*)(H + rb + c0) = h8;
    }
}

// ---------------- layer-3 act + final GEMV + log_softmax, fused ----------------
// Same single-pass act structure; h consumed on the fly by 10 LDS dot products.
__global__ __launch_bounds__(256) void act_final(const bf16_t* __restrict__ Z,
                                                 const float* __restrict__ mask,
                                                 const int* __restrict__ tids,
                                                 const bf16_t* __restrict__ W3b,
                                                 const float* __restrict__ b3,
                                                 float* __restrict__ mask_out,
                                                 float* __restrict__ out) {
    __shared__ __align__(16) bf16_t Ws[10 * 1024];   // 20 KB bf16
    #pragma unroll
    for (int i = threadIdx.x * 8; i < 10240; i += 2048)
        *(bf16x8*)(Ws + i) = *(const bf16x8*)(W3b + i);
    __syncthreads();

    const int wid  = threadIdx.x >> 6;
    const int lane = threadIdx.x & 63;
    const int row  = (int)blockIdx.x * 4 + wid;
    const size_t rb = (size_t)row * 1024;

    float p[16], mk[16];
    uint32_t m3 = 0, m4 = 0;
    float s3 = 0.f, s4 = 0.f;

    #pragma unroll
    for (int q = 0; q < 2; ++q) {
        const int c0 = (q * 64 + lane) * 8;
        const bf16x8 z8 = *(const bf16x8*)(Z + rb + c0);
        const int4   ta = *(const int4*)(tids + c0);
        const int4   tb = *(const int4*)(tids + c0 + 4);
        const float4 ma = *(const float4*)(mask + rb + c0);
        const float4 mb = *(const float4*)(mask + rb + c0 + 4);
        const int   tt8[8] = {ta.x, ta.y, ta.z, ta.w, tb.x, tb.y, tb.z, tb.w};
        const float mm8[8] = {ma.x, ma.y, ma.z, ma.w, mb.x, mb.y, mb.z, mb.w};
        #pragma unroll
        for (int j = 0; j < 8; ++j) {
            const int i = q * 8 + j;
            const float zz = (float)z8[j];
            const int tt = tt8[j];
            mk[i] = mm8[j];
            const float az = fabsf(zz);
            const float arg = (tt == 1) ? -2.f * az
                            : (tt == 2) ? -az
                            : (tt == 3) ? zz
                            : (tt == 4) ? -zz : 0.f;
            const float ee = __expf(arg);
            const float r1pe = __builtin_amdgcn_rcpf(1.f + ee);
            const float tha = (1.f - ee) * r1pe;
            const float tnh = (zz >= 0.f) ? tha : -tha;
            const float sg  = ((zz >= 0.f) ? 1.f : ee) * r1pe;
            const float gel = 0.5f * zz * (1.f + erff(zz * 0.70710678f));
            const float pre = (tt == 0) ? fmaxf(zz, 0.f)
                            : (tt == 1) ? tnh
                            : (tt == 2) ? sg
                            : (tt == 3) ? ee
                            : (tt == 4) ? ee
                            : (tt == 5) ? gel
                            : fmaxf(zz, 0.01f * zz);
            p[i] = pre;
            m3 |= (uint32_t)(tt == 3) << i;
            m4 |= (uint32_t)(tt == 4) << i;
            s3 += (tt == 3) ? ee : 0.f;
            s4 += (tt == 4) ? ee : 0.f;
        }
        *(float4*)(mask_out + rb + c0)     = ma;
        *(float4*)(mask_out + rb + c0 + 4) = mb;
    }
    #pragma unroll
    for (int off = 32; off > 0; off >>= 1) {
        s3 += __shfl_xor(s3, off);
        s4 += __shfl_xor(s4, off);
    }
    const float inv3 = 1.f / s3;
    const float inv4 = 1.f / s4;

    float acc[10];
    #pragma unroll
    for (int n = 0; n < 10; ++n) acc[n] = 0.f;

    #pragma unroll
    for (int q = 0; q < 2; ++q) {
        const int c0 = (q * 64 + lane) * 8;
        float h[8];
        #pragma unroll
        for (int j = 0; j < 8; ++j) {
            const int i = q * 8 + j;
            const float sc = ((m3 >> i) & 1) ? inv3 : ((m4 >> i) & 1) ? inv4 : 1.f;
            h[j] = p[i] * sc * mk[i] * 2.0f;
        }
        #pragma unroll
        for (int n = 0; n < 10; ++n) {
            const bf16x8 w8 = *(const bf16x8*)(Ws + n * 1024 + c0);
            float d = 0.f;
            #pragma unroll
            for (int j = 0; j < 8; ++j) d += h[j] * (float)w8[j];
            acc[n] += d;
        }
    }

    #pragma unroll
    for (int n = 0; n < 10; ++n)
        #pragma unroll
        for (int off = 32; off > 0; off >>= 1)
            acc[n] += __shfl_xor(acc[n], off);

    if (lane == 0) {
        float lg[10]; float mx = -1e30f;
        #pragma unroll
        for (int n = 0; n < 10; ++n) { lg[n] = acc[n] + b3[n]; mx = fmaxf(mx, lg[n]); }
        float se = 0.f;
        #pragma unroll
        for (int n = 0; n < 10; ++n) se += __expf(lg[n] - mx);
        const float lse = logf(se) + mx;
        #pragma unroll
        for (int n = 0; n < 10; ++n) out[(size_t)row * 10 + n] = lg[n] - lse;
    }
}

extern "C" void kernel_launch(void* const* d_in, const int* in_sizes, int n_in,
                              void* d_out, int out_size, void* d_ws, size_t ws_size,
                              hipStream_t stream) {
    (void)in_sizes; (void)n_in; (void)out_size; (void)ws_size;
    const float* x     = (const float*)d_in[0];
    const float* W0    = (const float*)d_in[1];
    const float* b0    = (const float*)d_in[2];
    const float* W1    = (const float*)d_in[3];
    const float* b1    = (const float*)d_in[4];
    const float* W2    = (const float*)d_in[5];
    const float* b2    = (const float*)d_in[6];
    const float* W3    = (const float*)d_in[7];
    const float* b3    = (const float*)d_in[8];
    const float* mask1 = (const float*)d_in[9];
    const float* mask2 = (const float*)d_in[10];
    const float* mask3 = (const float*)d_in[11];
    const int*   tids  = (const int*)d_in[12];

    float* out = (float*)d_out;
    float* mo1 = out + 327680;               // 32768*10
    float* mo2 = mo1 + 33554432;             // 32768*1024
    float* mo3 = mo2 + 33554432;

    char* ws = (char*)d_ws;
    bf16_t* xb  = (bf16_t*)ws;  ws += (size_t)32768 * 832 * 2;   // K padded to 832 (13*64)
    bf16_t* W0b = (bf16_t*)ws;  ws += (size_t)1024 * 832 * 2;
    bf16_t* W1b = (bf16_t*)ws;  ws += (size_t)1024 * 1024 * 2;
    bf16_t* W2b = (bf16_t*)ws;  ws += (size_t)1024 * 1024 * 2;
    bf16_t* W3b = (bf16_t*)ws;  ws += (size_t)16 * 1024 * 2;
    bf16_t* Zb  = (bf16_t*)ws;  ws += (size_t)32768 * 1024 * 2;
    bf16_t* hb  = (bf16_t*)ws;  ws += (size_t)32768 * 1024 * 2;
    // total workspace: ~194 MiB

    convert_pad<<<32768, 256, 0, stream>>>(x,  xb,  784, 832);
    convert_pad<<<1024,  256, 0, stream>>>(W0, W0b, 784, 832);
    convert_pad<<<1024,  256, 0, stream>>>(W1, W1b, 1024, 1024);
    convert_pad<<<1024,  256, 0, stream>>>(W2, W2b, 1024, 1024);
    convert_pad<<<10,    256, 0, stream>>>(W3, W3b, 1024, 1024);

    gemm_bt<<<2048, 256, 0, stream>>>(xb, W0b, b0, Zb, 832, 1024);
    act_kernel<<<8192, 256, 0, stream>>>(Zb, mask1, tids, hb, mo1);
    gemm_bt<<<2048, 256, 0, stream>>>(hb, W1b, b1, Zb, 1024, 1024);
    act_kernel<<<8192, 256, 0, stream>>>(Zb, mask2, tids + 1024, hb, mo2);
    gemm_bt<<<2048, 256, 0, stream>>>(hb, W2b, b2, Zb, 1024, 1024);
    act_final<<<8192, 256, 0, stream>>>(Zb, mask3, tids + 2048, W3b, b3, mo3, out);
}

// Round 4
// 1118.189 us; speedup vs baseline: 1.2440x; 1.0112x over previous
//
#include <hip/hip_runtime.h>
#include <hip/hip_bf16.h>
#include <cstdint>
#include <cstddef>

typedef __bf16 bf16_t;
typedef bf16_t bf16x8 __attribute__((ext_vector_type(8)));
typedef bf16_t bf16x4 __attribute__((ext_vector_type(4)));
typedef float f32x4 __attribute__((ext_vector_type(4)));

#define NEG_BIG (-1e30f)

// ---------------- fp32 -> bf16 convert with K padding ----------------
__global__ __launch_bounds__(256) void convert_pad(const float* __restrict__ src,
                                                   bf16_t* __restrict__ dst,
                                                   int incols, int outcols) {
    const int row = blockIdx.x;
    const float* s = src + (size_t)row * incols;
    bf16_t* d = dst + (size_t)row * outcols;
    const int n4 = outcols >> 2;
    for (int c = threadIdx.x; c < n4; c += blockDim.x) {
        const int col = c << 2;
        float4 v;
        if (col < incols) v = *(const float4*)(s + col);   // incols % 4 == 0
        else              v = make_float4(0.f, 0.f, 0.f, 0.f);
        bf16x4 o;
        o[0] = (bf16_t)v.x; o[1] = (bf16_t)v.y; o[2] = (bf16_t)v.z; o[3] = (bf16_t)v.w;
        *(bf16x4*)(d + col) = o;
    }
}

// ---------------- bf16 GEMM: Z = A[M,K] @ W[N,K]^T + bias, Z bf16 ----------------
// T3-minimum 2-phase: double-buffered LDS (2x16KB), next tile's global_load_lds
// issued BEFORE current tile's ds_read+MFMA; ONE __syncthreads per K-step (its
// implicit vmcnt(0) lands after the MFMA window -> load latency hidden).
// T2 swizzle (BK=32): LDS dest linear (required by global_load_lds), global source
// chunk pre-permuted by (lane&3)^((lane>>3)&3), read chunk = s ^ ((row>>1)&3).
#define BM 128
#define BN 128
#define BK 32

__global__ __launch_bounds__(256) void gemm_bt(const bf16_t* __restrict__ A,
                                               const bf16_t* __restrict__ W,
                                               const float* __restrict__ bias,
                                               bf16_t* __restrict__ Z,
                                               int K, int N) {
    __shared__ __align__(16) bf16_t As[2][BM * BK];   // 2 x 8 KB
    __shared__ __align__(16) bf16_t Bs[2][BN * BK];   // 2 x 8 KB
    const int tid  = threadIdx.x;
    const int wid  = tid >> 6;
    const int lane = tid & 63;

    // XCD-chunked bijective swizzle (gridDim.x % 8 == 0)
    const int bid = (int)blockIdx.x;
    const int cpx = (int)gridDim.x >> 3;
    const int swz = (bid & 7) * cpx + (bid >> 3);
    const int nbn = N >> 7;                 // N / BN
    const int n0 = (swz % nbn) * BN;
    const int m0 = (swz / nbn) * BM;

    const int wm = (wid >> 1) * 64;   // wave row offset within tile
    const int wn = (wid & 1) * 64;    // wave col offset within tile

    f32x4 acc[4][4] = {};

    // staging: 8 chunks of 1 KB per array; wave w owns chunks w*2+t (t=0,1).
    // chunk covers rows [idx*16, idx*16+16); lane -> row idx*16 + (lane>>2),
    // LDS 16B-chunk (lane&3). Source chunk = (lane&3) ^ ((lane>>3)&3)
    // [inverse of the read-side XOR; row bits 1-2 == (lane>>3)&3].
    const int srow = wid * 32 + (lane >> 2);
    const int scol = (((lane & 3) ^ ((lane >> 3) & 3)) << 3);   // elements
    const bf16_t* Ap0 = A + (size_t)(m0 + srow) * K + scol;
    const bf16_t* Ap1 = Ap0 + (size_t)16 * K;
    const bf16_t* Wp0 = W + (size_t)(n0 + srow) * K + scol;
    const bf16_t* Wp1 = Wp0 + (size_t)16 * K;

    const int ldsoff = (wid * 2) * 512;   // wave-uniform element offset

#define STAGE(b, k0)                                                                        \
    do {                                                                                    \
        __builtin_amdgcn_global_load_lds(                                                   \
            (const __attribute__((address_space(1))) void*)(Ap0 + (k0)),                    \
            (__attribute__((address_space(3))) void*)(&As[(b)][ldsoff]), 16, 0, 0);         \
        __builtin_amdgcn_global_load_lds(                                                   \
            (const __attribute__((address_space(1))) void*)(Ap1 + (k0)),                    \
            (__attribute__((address_space(3))) void*)(&As[(b)][ldsoff + 512]), 16, 0, 0);   \
        __builtin_amdgcn_global_load_lds(                                                   \
            (const __attribute__((address_space(1))) void*)(Wp0 + (k0)),                    \
            (__attribute__((address_space(3))) void*)(&Bs[(b)][ldsoff]), 16, 0, 0);         \
        __builtin_amdgcn_global_load_lds(                                                   \
            (const __attribute__((address_space(1))) void*)(Wp1 + (k0)),                    \
            (__attribute__((address_space(3))) void*)(&Bs[(b)][ldsoff + 512]), 16, 0, 0);   \
    } while (0)

    const int nk = K >> 5;   // K / BK
    STAGE(0, 0);
    __syncthreads();   // implicit vmcnt(0) drain of prologue stage

    // read-side addressing (constant across iterations)
    const int arow = wm + (lane & 15);
    const int brow = wn + (lane & 15);
    const int s    = lane >> 4;
    const int ka   = ((s ^ ((arow >> 1) & 3)) << 3);   // swizzled k-chunk, elements
    const int kb   = ((s ^ ((brow >> 1) & 3)) << 3);

    int cur = 0;
    for (int t = 0; t < nk; ++t) {
        if (t + 1 < nk) STAGE(cur ^ 1, (t + 1) << 5);   // prefetch next tile

        const bf16_t* Ac = &As[cur][0];
        const bf16_t* Bc = &Bs[cur][0];
        bf16x8 af[4], bfr[4];
        #pragma unroll
        for (int i = 0; i < 4; ++i)
            af[i] = *(const bf16x8*)(Ac + (arow + i * 16) * BK + ka);
        #pragma unroll
        for (int j = 0; j < 4; ++j)
            bfr[j] = *(const bf16x8*)(Bc + (brow + j * 16) * BK + kb);
        #pragma unroll
        for (int i = 0; i < 4; ++i)
            #pragma unroll
            for (int j = 0; j < 4; ++j)
                acc[i][j] = __builtin_amdgcn_mfma_f32_16x16x32_bf16(af[i], bfr[j], acc[i][j], 0, 0, 0);

        __syncthreads();   // one barrier/iter: drains prefetch, protects buf reuse
        cur ^= 1;
    }
#undef STAGE

    // epilogue: C/D layout col=lane&15, row=(lane>>4)*4+r
    const int cq = lane >> 4;
    const int cl = lane & 15;
    #pragma unroll
    for (int j = 0; j < 4; ++j) {
        const int col = n0 + wn + j * 16 + cl;
        const float bj = bias[col];
        #pragma unroll
        for (int i = 0; i < 4; ++i) {
            const int row = m0 + wm + i * 16 + cq * 4;
            #pragma unroll
            for (int r = 0; r < 4; ++r)
                Z[(size_t)(row + r) * N + col] = (bf16_t)(acc[i][j][r] + bj);
        }
    }
}

// ---------------- mixed activation + dropout-mask + mask passthrough ----------------
// One WAVE per row (64 lanes x 8 cols x 2). Single compute pass: activation is fully
// evaluated BEFORE the softmax-sum reduction (softmax elems carry exp; only the
// 1/sum scale is deferred). Type kept as two 16-bit masks (2 VGPRs, not 16).
__global__ __launch_bounds__(256) void act_kernel(const bf16_t* __restrict__ Z,
                                                  const float* __restrict__ mask,
                                                  const int* __restrict__ tids,
                                                  bf16_t* __restrict__ H,
                                                  float* __restrict__ mask_out) {
    const int wid  = threadIdx.x >> 6;
    const int lane = threadIdx.x & 63;
    const int row  = (int)blockIdx.x * 4 + wid;
    const size_t rb = (size_t)row * 1024;

    float p[16], mk[16];
    uint32_t m3 = 0, m4 = 0;
    float s3 = 0.f, s4 = 0.f;

    #pragma unroll
    for (int q = 0; q < 2; ++q) {
        const int c0 = (q * 64 + lane) * 8;
        const bf16x8 z8 = *(const bf16x8*)(Z + rb + c0);
        const int4   ta = *(const int4*)(tids + c0);
        const int4   tb = *(const int4*)(tids + c0 + 4);
        const float4 ma = *(const float4*)(mask + rb + c0);
        const float4 mb = *(const float4*)(mask + rb + c0 + 4);
        const int   tt8[8] = {ta.x, ta.y, ta.z, ta.w, tb.x, tb.y, tb.z, tb.w};
        const float mm8[8] = {ma.x, ma.y, ma.z, ma.w, mb.x, mb.y, mb.z, mb.w};
        #pragma unroll
        for (int j = 0; j < 8; ++j) {
            const int i = q * 8 + j;
            const float zz = (float)z8[j];
            const int tt = tt8[j];
            mk[i] = mm8[j];
            const float az = fabsf(zz);
            const float arg = (tt == 1) ? -2.f * az
                            : (tt == 2) ? -az
                            : (tt == 3) ? zz
                            : (tt == 4) ? -zz : 0.f;
            const float ee = __expf(arg);
            const float r1pe = __builtin_amdgcn_rcpf(1.f + ee);
            const float tha = (1.f - ee) * r1pe;               // tanh(|z|)
            const float tnh = (zz >= 0.f) ? tha : -tha;
            const float sg  = ((zz >= 0.f) ? 1.f : ee) * r1pe; // sigmoid
            const float gel = 0.5f * zz * (1.f + erff(zz * 0.70710678f));
            const float pre = (tt == 0) ? fmaxf(zz, 0.f)
                            : (tt == 1) ? tnh
                            : (tt == 2) ? sg
                            : (tt == 3) ? ee
                            : (tt == 4) ? ee
                            : (tt == 5) ? gel
                            : fmaxf(zz, 0.01f * zz);           // lrelu
            p[i] = pre;
            m3 |= (uint32_t)(tt == 3) << i;
            m4 |= (uint32_t)(tt == 4) << i;
            s3 += (tt == 3) ? ee : 0.f;
            s4 += (tt == 4) ? ee : 0.f;
        }
        *(float4*)(mask_out + rb + c0)     = ma;
        *(float4*)(mask_out + rb + c0 + 4) = mb;
    }
    #pragma unroll
    for (int off = 32; off > 0; off >>= 1) {
        s3 += __shfl_xor(s3, off);
        s4 += __shfl_xor(s4, off);
    }
    const float inv3 = 1.f / s3;   // inf only if no tid==3 col: never selected then
    const float inv4 = 1.f / s4;

    #pragma unroll
    for (int q = 0; q < 2; ++q) {
        const int c0 = (q * 64 + lane) * 8;
        bf16x8 h8;
        #pragma unroll
        for (int j = 0; j < 8; ++j) {
            const int i = q * 8 + j;
            const float sc = ((m3 >> i) & 1) ? inv3 : ((m4 >> i) & 1) ? inv4 : 1.f;
            h8[j] = (bf16_t)(p[i] * sc * mk[i] * 2.0f);        // KEEP_SCALE = 2
        }
        *(bf16x8*)(H + rb + c0) = h8;
    }
}

// ---------------- layer-3 act + final GEMV + log_softmax, fused ----------------
// Same single-pass act structure; h consumed on the fly by 10 LDS dot products.
__global__ __launch_bounds__(256) void act_final(const bf16_t* __restrict__ Z,
                                                 const float* __restrict__ mask,
                                                 const int* __restrict__ tids,
                                                 const bf16_t* __restrict__ W3b,
                                                 const float* __restrict__ b3,
                                                 float* __restrict__ mask_out,
                                                 float* __restrict__ out) {
    __shared__ __align__(16) bf16_t Ws[10 * 1024];   // 20 KB bf16
    #pragma unroll
    for (int i = threadIdx.x * 8; i < 10240; i += 2048)
        *(bf16x8*)(Ws + i) = *(const bf16x8*)(W3b + i);
    __syncthreads();

    const int wid  = threadIdx.x >> 6;
    const int lane = threadIdx.x & 63;
    const int row  = (int)blockIdx.x * 4 + wid;
    const size_t rb = (size_t)row * 1024;

    float p[16], mk[16];
    uint32_t m3 = 0, m4 = 0;
    float s3 = 0.f, s4 = 0.f;

    #pragma unroll
    for (int q = 0; q < 2; ++q) {
        const int c0 = (q * 64 + lane) * 8;
        const bf16x8 z8 = *(const bf16x8*)(Z + rb + c0);
        const int4   ta = *(const int4*)(tids + c0);
        const int4   tb = *(const int4*)(tids + c0 + 4);
        const float4 ma = *(const float4*)(mask + rb + c0);
        const float4 mb = *(const float4*)(mask + rb + c0 + 4);
        const int   tt8[8] = {ta.x, ta.y, ta.z, ta.w, tb.x, tb.y, tb.z, tb.w};
        const float mm8[8] = {ma.x, ma.y, ma.z, ma.w, mb.x, mb.y, mb.z, mb.w};
        #pragma unroll
        for (int j = 0; j < 8; ++j) {
            const int i = q * 8 + j;
            const float zz = (float)z8[j];
            const int tt = tt8[j];
            mk[i] = mm8[j];
            const float az = fabsf(zz);
            const float arg = (tt == 1) ? -2.f * az
                            : (tt == 2) ? -az
                            : (tt == 3) ? zz
                            : (tt == 4) ? -zz : 0.f;
            const float ee = __expf(arg);
            const float r1pe = __builtin_amdgcn_rcpf(1.f + ee);
            const float tha = (1.f - ee) * r1pe;
            const float tnh = (zz >= 0.f) ? tha : -tha;
            const float sg  = ((zz >= 0.f) ? 1.f : ee) * r1pe;
            const float gel = 0.5f * zz * (1.f + erff(zz * 0.70710678f));
            const float pre = (tt == 0) ? fmaxf(zz, 0.f)
                            : (tt == 1) ? tnh
                            : (tt == 2) ? sg
                            : (tt == 3) ? ee
                            : (tt == 4) ? ee
                            : (tt == 5) ? gel
                            : fmaxf(zz, 0.01f * zz);
            p[i] = pre;
            m3 |= (uint32_t)(tt == 3) << i;
            m4 |= (uint32_t)(tt == 4) << i;
            s3 += (tt == 3) ? ee : 0.f;
            s4 += (tt == 4) ? ee : 0.f;
        }
        *(float4*)(mask_out + rb + c0)     = ma;
        *(float4*)(mask_out + rb + c0 + 4) = mb;
    }
    #pragma unroll
    for (int off = 32; off > 0; off >>= 1) {
        s3 += __shfl_xor(s3, off);
        s4 += __shfl_xor(s4, off);
    }
    const float inv3 = 1.f / s3;
    const float inv4 = 1.f / s4;

    float acc[10];
    #pragma unroll
    for (int n = 0; n < 10; ++n) acc[n] = 0.f;

    #pragma unroll
    for (int q = 0; q < 2; ++q) {
        const int c0 = (q * 64 + lane) * 8;
        float h[8];
        #pragma unroll
        for (int j = 0; j < 8; ++j) {
            const int i = q * 8 + j;
            const float sc = ((m3 >> i) & 1) ? inv3 : ((m4 >> i) & 1) ? inv4 : 1.f;
            h[j] = p[i] * sc * mk[i] * 2.0f;
        }
        #pragma unroll
        for (int n = 0; n < 10; ++n) {
            const bf16x8 w8 = *(const bf16x8*)(Ws + n * 1024 + c0);
            float d = 0.f;
            #pragma unroll
            for (int j = 0; j < 8; ++j) d += h[j] * (float)w8[j];
            acc[n] += d;
        }
    }

    #pragma unroll
    for (int n = 0; n < 10; ++n)
        #pragma unroll
        for (int off = 32; off > 0; off >>= 1)
            acc[n] += __shfl_xor(acc[n], off);

    if (lane == 0) {
        float lg[10]; float mx = -1e30f;
        #pragma unroll
        for (int n = 0; n < 10; ++n) { lg[n] = acc[n] + b3[n]; mx = fmaxf(mx, lg[n]); }
        float se = 0.f;
        #pragma unroll
        for (int n = 0; n < 10; ++n) se += __expf(lg[n] - mx);
        const float lse = logf(se) + mx;
        #pragma unroll
        for (int n = 0; n < 10; ++n) out[(size_t)row * 10 + n] = lg[n] - lse;
    }
}

extern "C" void kernel_launch(void* const* d_in, const int* in_sizes, int n_in,
                              void* d_out, int out_size, void* d_ws, size_t ws_size,
                              hipStream_t stream) {
    (void)in_sizes; (void)n_in; (void)out_size; (void)ws_size;
    const float* x     = (const float*)d_in[0];
    const float* W0    = (const float*)d_in[1];
    const float* b0    = (const float*)d_in[2];
    const float* W1    = (const float*)d_in[3];
    const float* b1    = (const float*)d_in[4];
    const float* W2    = (const float*)d_in[5];
    const float* b2    = (const float*)d_in[6];
    const float* W3    = (const float*)d_in[7];
    const float* b3    = (const float*)d_in[8];
    const float* mask1 = (const float*)d_in[9];
    const float* mask2 = (const float*)d_in[10];
    const float* mask3 = (const float*)d_in[11];
    const int*   tids  = (const int*)d_in[12];

    float* out = (float*)d_out;
    float* mo1 = out + 327680;               // 32768*10
    float* mo2 = mo1 + 33554432;             // 32768*1024
    float* mo3 = mo2 + 33554432;

    char* ws = (char*)d_ws;
    bf16_t* xb  = (bf16_t*)ws;  ws += (size_t)32768 * 800 * 2;   // K=800 (25*32)
    bf16_t* W0b = (bf16_t*)ws;  ws += (size_t)1024 * 800 * 2;
    bf16_t* W1b = (bf16_t*)ws;  ws += (size_t)1024 * 1024 * 2;
    bf16_t* W2b = (bf16_t*)ws;  ws += (size_t)1024 * 1024 * 2;
    bf16_t* W3b = (bf16_t*)ws;  ws += (size_t)16 * 1024 * 2;
    bf16_t* Zb  = (bf16_t*)ws;  ws += (size_t)32768 * 1024 * 2;
    bf16_t* hb  = (bf16_t*)ws;  ws += (size_t)32768 * 1024 * 2;
    // total workspace: ~192 MiB

    convert_pad<<<32768, 256, 0, stream>>>(x,  xb,  784, 800);
    convert_pad<<<1024,  256, 0, stream>>>(W0, W0b, 784, 800);
    convert_pad<<<1024,  256, 0, stream>>>(W1, W1b, 1024, 1024);
    convert_pad<<<1024,  256, 0, stream>>>(W2, W2b, 1024, 1024);
    convert_pad<<<10,    256, 0, stream>>>(W3, W3b, 1024, 1024);

    gemm_bt<<<2048, 256, 0, stream>>>(xb, W0b, b0, Zb, 800, 1024);
    act_kernel<<<8192, 256, 0, stream>>>(Zb, mask1, tids, hb, mo1);
    gemm_bt<<<2048, 256, 0, stream>>>(hb, W1b, b1, Zb, 1024, 1024);
    act_kernel<<<8192, 256, 0, stream>>>(Zb, mask2, tids + 1024, hb, mo2);
    gemm_bt<<<2048, 256, 0, stream>>>(hb, W2b, b2, Zb, 1024, 1024);
    act_final<<<8192, 256, 0, stream>>>(Zb, mask3, tids + 2048, W3b, b3, mo3, out);
}

// Round 5
// 1068.102 us; speedup vs baseline: 1.3023x; 1.0469x over previous
//
#include <hip/hip_runtime.h>
#include <hip/hip_bf16.h>
#include <cstdint>
#include <cstddef>

typedef __bf16 bf16_t;
typedef bf16_t bf16x8 __attribute__((ext_vector_type(8)));
typedef bf16_t bf16x4 __attribute__((ext_vector_type(4)));
typedef float f32x4 __attribute__((ext_vector_type(4)));

#define NEG_BIG (-1e30f)

// ---------------- fp32 -> bf16 convert with K padding ----------------
__global__ __launch_bounds__(256) void convert_pad(const float* __restrict__ src,
                                                   bf16_t* __restrict__ dst,
                                                   int incols, int outcols) {
    const int row = blockIdx.x;
    const float* s = src + (size_t)row * incols;
    bf16_t* d = dst + (size_t)row * outcols;
    const int n4 = outcols >> 2;
    for (int c = threadIdx.x; c < n4; c += blockDim.x) {
        const int col = c << 2;
        float4 v;
        if (col < incols) v = *(const float4*)(s + col);   // incols % 4 == 0
        else              v = make_float4(0.f, 0.f, 0.f, 0.f);
        bf16x4 o;
        o[0] = (bf16_t)v.x; o[1] = (bf16_t)v.y; o[2] = (bf16_t)v.z; o[3] = (bf16_t)v.w;
        *(bf16x4*)(d + col) = o;
    }
}

// ---------------- bf16 GEMM: Z = A[M,K] @ W[N,K]^T + bias, Z bf16 ----------------
// Geometry: BM=128 x BN=256, 4 waves (256 thr), wave tile 128x64 (acc[8][4]).
//   -> 384 LDS-bytes per MFMA (vs 512 for 4x4 wave tiles): LDS no longer 1:1 with MFMA.
// Pipeline: 3 LDS buffers (3 x 24 KB), stage tile t+2 each iter, counted
//   s_waitcnt vmcnt(6) at iter end (6 newest loads stay in flight across the
//   barrier -> load latency spans a full compute phase). lgkmcnt(0) before the
//   raw s_barrier guarantees cross-wave LDS WAR safety (8-phase-template pattern).
// T2 swizzle (carried from verified round-4 kernel): LDS dest linear (required
//   by global_load_lds), global source 16B-slot pre-permuted by (lane&3)^((lane>>3)&3),
//   read k-chunk = (lane>>4) ^ ((row>>1)&3).
// Epilogue: acc -> LDS (XOR-swizzled, reuses staging smem) -> coalesced bf16x8
//   stores in 512-byte runs (replaces scattered 2B stores).
#define BM 128
#define BN 256
#define BK 32

__global__ __launch_bounds__(256, 2) void gemm_bt(const bf16_t* __restrict__ A,
                                                  const bf16_t* __restrict__ W,
                                                  const float* __restrict__ bias,
                                                  bf16_t* __restrict__ Z,
                                                  int K, int N) {
    __shared__ __align__(16) char smem[73728];   // 3 x 24 KB staging, 64 KB C-stage
    bf16_t* sb = (bf16_t*)smem;
    const int tid  = threadIdx.x;
    const int wid  = tid >> 6;
    const int lane = tid & 63;

    // XCD-chunked bijective swizzle (gridDim.x % 8 == 0)
    const int bid = (int)blockIdx.x;
    const int cpx = (int)gridDim.x >> 3;
    const int swz = (bid & 7) * cpx + (bid >> 3);
    const int nbn = N >> 8;                 // N / BN
    const int n0 = (swz % nbn) * BN;
    const int m0 = (swz / nbn) * BM;

    f32x4 acc[8][4] = {};

    // staging: A-tile 128x32 = 8 chunks (16 rows x 32 cols, 1 KB each), wave w owns
    // chunks 2w,2w+1; B-tile 256x32 = 16 chunks, wave w owns 4w..4w+3. 6 loads/thread.
    const int srA  = lane >> 2;
    const int scol = (((lane & 3) ^ ((lane >> 3) & 3)) << 3);   // pre-swizzled 16B slot
    const bf16_t* Ap = A + (size_t)(m0 + wid * 32 + srA) * K + scol;
    const bf16_t* Wp = W + (size_t)(n0 + wid * 64 + srA) * K + scol;
    const size_t K16 = (size_t)16 * K;

    const int aoff = (wid * 2) * 512;          // elems, within buffer
    const int boff = 4096 + (wid * 4) * 512;   // B region starts at 8 KB

#define STAGE(b, kt)                                                                          \
    do {                                                                                      \
        const int k0_ = (kt) * BK;                                                            \
        bf16_t* dst_ = sb + (b) * 12288;                                                      \
        __builtin_amdgcn_global_load_lds(                                                     \
            (const __attribute__((address_space(1))) void*)(Ap + k0_),                        \
            (__attribute__((address_space(3))) void*)(dst_ + aoff), 16, 0, 0);                \
        __builtin_amdgcn_global_load_lds(                                                     \
            (const __attribute__((address_space(1))) void*)(Ap + k0_ + K16),                  \
            (__attribute__((address_space(3))) void*)(dst_ + aoff + 512), 16, 0, 0);          \
        __builtin_amdgcn_global_load_lds(                                                     \
            (const __attribute__((address_space(1))) void*)(Wp + k0_),                        \
            (__attribute__((address_space(3))) void*)(dst_ + boff), 16, 0, 0);                \
        __builtin_amdgcn_global_load_lds(                                                     \
            (const __attribute__((address_space(1))) void*)(Wp + k0_ + K16),                  \
            (__attribute__((address_space(3))) void*)(dst_ + boff + 512), 16, 0, 0);          \
        __builtin_amdgcn_global_load_lds(                                                     \
            (const __attribute__((address_space(1))) void*)(Wp + k0_ + 2 * K16),              \
            (__attribute__((address_space(3))) void*)(dst_ + boff + 1024), 16, 0, 0);         \
        __builtin_amdgcn_global_load_lds(                                                     \
            (const __attribute__((address_space(1))) void*)(Wp + k0_ + 3 * K16),              \
            (__attribute__((address_space(3))) void*)(dst_ + boff + 1536), 16, 0, 0);         \
    } while (0)

    const int nk = K >> 5;   // >= 25 always
    STAGE(0, 0);
    STAGE(1, 1);
    asm volatile("s_waitcnt vmcnt(6)" ::: "memory");   // stage 0 complete
    __builtin_amdgcn_s_barrier();
    asm volatile("" ::: "memory");

    // read-side addressing (constant across iterations)
    const int ar = lane & 15;                  // A row base (all waves share A)
    const int br = wid * 64 + (lane & 15);     // B row base (wave's 64-col strip)
    const int s_ = lane >> 4;
    const int ka = ((s_ ^ ((ar >> 1) & 3)) << 3);   // swizzled k-chunk, elems
    const int kb = ((s_ ^ ((br >> 1) & 3)) << 3);

    int cb = 0;       // buffer being computed
    int pb = 2;       // buffer to stage into (t+2)%3
    for (int t = 0; t < nk; ++t) {
        if (t + 2 < nk) STAGE(pb, t + 2);

        const bf16_t* As_ = sb + cb * 12288;
        const bf16_t* Bs_ = As_ + 4096;
        bf16x8 af[8], bfr[4];
        #pragma unroll
        for (int j = 0; j < 4; ++j)
            bfr[j] = *(const bf16x8*)(Bs_ + (br + j * 16) * 32 + kb);
        #pragma unroll
        for (int i = 0; i < 8; ++i)
            af[i] = *(const bf16x8*)(As_ + (ar + i * 16) * 32 + ka);
        #pragma unroll
        for (int i = 0; i < 8; ++i)
            #pragma unroll
            for (int j = 0; j < 4; ++j)
                acc[i][j] = __builtin_amdgcn_mfma_f32_16x16x32_bf16(af[i], bfr[j], acc[i][j], 0, 0, 0);

        asm volatile("s_waitcnt lgkmcnt(0)" ::: "memory");   // all LDS reads processed
        if (t + 2 < nk) asm volatile("s_waitcnt vmcnt(6)" ::: "memory");  // stage t+1 done
        else            asm volatile("s_waitcnt vmcnt(0)" ::: "memory");  // drain tail
        __builtin_amdgcn_s_barrier();
        asm volatile("" ::: "memory");

        cb = (cb == 2) ? 0 : cb + 1;
        pb = (pb == 2) ? 0 : pb + 1;
    }
#undef STAGE

    // ---- epilogue: bias + cvt -> LDS (swizzled) -> coalesced 512B-run stores ----
    // C/D layout: col=lane&15, row=(lane>>4)*4+r. Logical C-tile [128][256] bf16.
    const int cq = lane >> 4;
    const int cl = lane & 15;
    #pragma unroll
    for (int j = 0; j < 4; ++j) {
        const int col = wid * 64 + j * 16 + cl;
        const float bj = bias[n0 + col];
        #pragma unroll
        for (int i = 0; i < 8; ++i) {
            #pragma unroll
            for (int r = 0; r < 4; ++r) {
                const int row = i * 16 + cq * 4 + r;
                const int bo = (row * 512 + col * 2) ^ ((row & 7) << 4);
                *(bf16_t*)(smem + bo) = (bf16_t)(acc[i][j][r] + bj);
            }
        }
    }
    __syncthreads();
    #pragma unroll
    for (int p = 0; p < 16; ++p) {
        const int row  = p * 8 + (tid >> 5);
        const int slot = tid & 31;
        const int bo = (row * 512 + slot * 16) ^ ((row & 7) << 4);
        const bf16x8 v = *(const bf16x8*)(smem + bo);
        *(bf16x8*)(Z + (size_t)(m0 + row) * N + n0 + slot * 8) = v;
    }
}

// ---------------- mixed activation + dropout-mask + mask passthrough ----------------
// One WAVE per row (64 lanes x 8 cols x 2). Single compute pass: activation is fully
// evaluated BEFORE the softmax-sum reduction (softmax elems carry exp; only the
// 1/sum scale is deferred). Type kept as two 16-bit masks (2 VGPRs, not 16).
__global__ __launch_bounds__(256) void act_kernel(const bf16_t* __restrict__ Z,
                                                  const float* __restrict__ mask,
                                                  const int* __restrict__ tids,
                                                  bf16_t* __restrict__ H,
                                                  float* __restrict__ mask_out) {
    const int wid  = threadIdx.x >> 6;
    const int lane = threadIdx.x & 63;
    const int row  = (int)blockIdx.x * 4 + wid;
    const size_t rb = (size_t)row * 1024;

    float p[16], mk[16];
    uint32_t m3 = 0, m4 = 0;
    float s3 = 0.f, s4 = 0.f;

    #pragma unroll
    for (int q = 0; q < 2; ++q) {
        const int c0 = (q * 64 + lane) * 8;
        const bf16x8 z8 = *(const bf16x8*)(Z + rb + c0);
        const int4   ta = *(const int4*)(tids + c0);
        const int4   tb = *(const int4*)(tids + c0 + 4);
        const float4 ma = *(const float4*)(mask + rb + c0);
        const float4 mb = *(const float4*)(mask + rb + c0 + 4);
        const int   tt8[8] = {ta.x, ta.y, ta.z, ta.w, tb.x, tb.y, tb.z, tb.w};
        const float mm8[8] = {ma.x, ma.y, ma.z, ma.w, mb.x, mb.y, mb.z, mb.w};
        #pragma unroll
        for (int j = 0; j < 8; ++j) {
            const int i = q * 8 + j;
            const float zz = (float)z8[j];
            const int tt = tt8[j];
            mk[i] = mm8[j];
            const float az = fabsf(zz);
            const float arg = (tt == 1) ? -2.f * az
                            : (tt == 2) ? -az
                            : (tt == 3) ? zz
                            : (tt == 4) ? -zz : 0.f;
            const float ee = __expf(arg);
            const float r1pe = __builtin_amdgcn_rcpf(1.f + ee);
            const float tha = (1.f - ee) * r1pe;               // tanh(|z|)
            const float tnh = (zz >= 0.f) ? tha : -tha;
            const float sg  = ((zz >= 0.f) ? 1.f : ee) * r1pe; // sigmoid
            const float gel = 0.5f * zz * (1.f + erff(zz * 0.70710678f));
            const float pre = (tt == 0) ? fmaxf(zz, 0.f)
                            : (tt == 1) ? tnh
                            : (tt == 2) ? sg
                            : (tt == 3) ? ee
                            : (tt == 4) ? ee
                            : (tt == 5) ? gel
                            : fmaxf(zz, 0.01f * zz);           // lrelu
            p[i] = pre;
            m3 |= (uint32_t)(tt == 3) << i;
            m4 |= (uint32_t)(tt == 4) << i;
            s3 += (tt == 3) ? ee : 0.f;
            s4 += (tt == 4) ? ee : 0.f;
        }
        *(float4*)(mask_out + rb + c0)     = ma;
        *(float4*)(mask_out + rb + c0 + 4) = mb;
    }
    #pragma unroll
    for (int off = 32; off > 0; off >>= 1) {
        s3 += __shfl_xor(s3, off);
        s4 += __shfl_xor(s4, off);
    }
    const float inv3 = 1.f / s3;   // inf only if no tid==3 col: never selected then
    const float inv4 = 1.f / s4;

    #pragma unroll
    for (int q = 0; q < 2; ++q) {
        const int c0 = (q * 64 + lane) * 8;
        bf16x8 h8;
        #pragma unroll
        for (int j = 0; j < 8; ++j) {
            const int i = q * 8 + j;
            const float sc = ((m3 >> i) & 1) ? inv3 : ((m4 >> i) & 1) ? inv4 : 1.f;
            h8[j] = (bf16_t)(p[i] * sc * mk[i] * 2.0f);        // KEEP_SCALE = 2
        }
        *(bf16x8*)(H + rb + c0) = h8;
    }
}

// ---------------- layer-3 act + final GEMV + log_softmax, fused ----------------
// Same single-pass act structure; h consumed on the fly by 10 LDS dot products.
__global__ __launch_bounds__(256) void act_final(const bf16_t* __restrict__ Z,
                                                 const float* __restrict__ mask,
                                                 const int* __restrict__ tids,
                                                 const bf16_t* __restrict__ W3b,
                                                 const float* __restrict__ b3,
                                                 float* __restrict__ mask_out,
                                                 float* __restrict__ out) {
    __shared__ __align__(16) bf16_t Ws[10 * 1024];   // 20 KB bf16
    #pragma unroll
    for (int i = threadIdx.x * 8; i < 10240; i += 2048)
        *(bf16x8*)(Ws + i) = *(const bf16x8*)(W3b + i);
    __syncthreads();

    const int wid  = threadIdx.x >> 6;
    const int lane = threadIdx.x & 63;
    const int row  = (int)blockIdx.x * 4 + wid;
    const size_t rb = (size_t)row * 1024;

    float p[16], mk[16];
    uint32_t m3 = 0, m4 = 0;
    float s3 = 0.f, s4 = 0.f;

    #pragma unroll
    for (int q = 0; q < 2; ++q) {
        const int c0 = (q * 64 + lane) * 8;
        const bf16x8 z8 = *(const bf16x8*)(Z + rb + c0);
        const int4   ta = *(const int4*)(tids + c0);
        const int4   tb = *(const int4*)(tids + c0 + 4);
        const float4 ma = *(const float4*)(mask + rb + c0);
        const float4 mb = *(const float4*)(mask + rb + c0 + 4);
        const int   tt8[8] = {ta.x, ta.y, ta.z, ta.w, tb.x, tb.y, tb.z, tb.w};
        const float mm8[8] = {ma.x, ma.y, ma.z, ma.w, mb.x, mb.y, mb.z, mb.w};
        #pragma unroll
        for (int j = 0; j < 8; ++j) {
            const int i = q * 8 + j;
            const float zz = (float)z8[j];
            const int tt = tt8[j];
            mk[i] = mm8[j];
            const float az = fabsf(zz);
            const float arg = (tt == 1) ? -2.f * az
                            : (tt == 2) ? -az
                            : (tt == 3) ? zz
                            : (tt == 4) ? -zz : 0.f;
            const float ee = __expf(arg);
            const float r1pe = __builtin_amdgcn_rcpf(1.f + ee);
            const float tha = (1.f - ee) * r1pe;
            const float tnh = (zz >= 0.f) ? tha : -tha;
            const float sg  = ((zz >= 0.f) ? 1.f : ee) * r1pe;
            const float gel = 0.5f * zz * (1.f + erff(zz * 0.70710678f));
            const float pre = (tt == 0) ? fmaxf(zz, 0.f)
                            : (tt == 1) ? tnh
                            : (tt == 2) ? sg
                            : (tt == 3) ? ee
                            : (tt == 4) ? ee
                            : (tt == 5) ? gel
                            : fmaxf(zz, 0.01f * zz);
            p[i] = pre;
            m3 |= (uint32_t)(tt == 3) << i;
            m4 |= (uint32_t)(tt == 4) << i;
            s3 += (tt == 3) ? ee : 0.f;
            s4 += (tt == 4) ? ee : 0.f;
        }
        *(float4*)(mask_out + rb + c0)     = ma;
        *(float4*)(mask_out + rb + c0 + 4) = mb;
    }
    #pragma unroll
    for (int off = 32; off > 0; off >>= 1) {
        s3 += __shfl_xor(s3, off);
        s4 += __shfl_xor(s4, off);
    }
    const float inv3 = 1.f / s3;
    const float inv4 = 1.f / s4;

    float acc[10];
    #pragma unroll
    for (int n = 0; n < 10; ++n) acc[n] = 0.f;

    #pragma unroll
    for (int q = 0; q < 2; ++q) {
        const int c0 = (q * 64 + lane) * 8;
        float h[8];
        #pragma unroll
        for (int j = 0; j < 8; ++j) {
            const int i = q * 8 + j;
            const float sc = ((m3 >> i) & 1) ? inv3 : ((m4 >> i) & 1) ? inv4 : 1.f;
            h[j] = p[i] * sc * mk[i] * 2.0f;
        }
        #pragma unroll
        for (int n = 0; n < 10; ++n) {
            const bf16x8 w8 = *(const bf16x8*)(Ws + n * 1024 + c0);
            float d = 0.f;
            #pragma unroll
            for (int j = 0; j < 8; ++j) d += h[j] * (float)w8[j];
            acc[n] += d;
        }
    }

    #pragma unroll
    for (int n = 0; n < 10; ++n)
        #pragma unroll
        for (int off = 32; off > 0; off >>= 1)
            acc[n] += __shfl_xor(acc[n], off);

    if (lane == 0) {
        float lg[10]; float mx = -1e30f;
        #pragma unroll
        for (int n = 0; n < 10; ++n) { lg[n] = acc[n] + b3[n]; mx = fmaxf(mx, lg[n]); }
        float se = 0.f;
        #pragma unroll
        for (int n = 0; n < 10; ++n) se += __expf(lg[n] - mx);
        const float lse = logf(se) + mx;
        #pragma unroll
        for (int n = 0; n < 10; ++n) out[(size_t)row * 10 + n] = lg[n] - lse;
    }
}

extern "C" void kernel_launch(void* const* d_in, const int* in_sizes, int n_in,
                              void* d_out, int out_size, void* d_ws, size_t ws_size,
                              hipStream_t stream) {
    (void)in_sizes; (void)n_in; (void)out_size; (void)ws_size;
    const float* x     = (const float*)d_in[0];
    const float* W0    = (const float*)d_in[1];
    const float* b0    = (const float*)d_in[2];
    const float* W1    = (const float*)d_in[3];
    const float* b1    = (const float*)d_in[4];
    const float* W2    = (const float*)d_in[5];
    const float* b2    = (const float*)d_in[6];
    const float* W3    = (const float*)d_in[7];
    const float* b3    = (const float*)d_in[8];
    const float* mask1 = (const float*)d_in[9];
    const float* mask2 = (const float*)d_in[10];
    const float* mask3 = (const float*)d_in[11];
    const int*   tids  = (const int*)d_in[12];

    float* out = (float*)d_out;
    float* mo1 = out + 327680;               // 32768*10
    float* mo2 = mo1 + 33554432;             // 32768*1024
    float* mo3 = mo2 + 33554432;

    char* ws = (char*)d_ws;
    bf16_t* xb  = (bf16_t*)ws;  ws += (size_t)32768 * 800 * 2;   // K=800 (25*32)
    bf16_t* W0b = (bf16_t*)ws;  ws += (size_t)1024 * 800 * 2;
    bf16_t* W1b = (bf16_t*)ws;  ws += (size_t)1024 * 1024 * 2;
    bf16_t* W2b = (bf16_t*)ws;  ws += (size_t)1024 * 1024 * 2;
    bf16_t* W3b = (bf16_t*)ws;  ws += (size_t)16 * 1024 * 2;
    bf16_t* Zb  = (bf16_t*)ws;  ws += (size_t)32768 * 1024 * 2;
    bf16_t* hb  = (bf16_t*)ws;  ws += (size_t)32768 * 1024 * 2;
    // total workspace: ~192 MiB

    convert_pad<<<32768, 256, 0, stream>>>(x,  xb,  784, 800);
    convert_pad<<<1024,  256, 0, stream>>>(W0, W0b, 784, 800);
    convert_pad<<<1024,  256, 0, stream>>>(W1, W1b, 1024, 1024);
    convert_pad<<<1024,  256, 0, stream>>>(W2, W2b, 1024, 1024);
    convert_pad<<<10,    256, 0, stream>>>(W3, W3b, 1024, 1024);

    gemm_bt<<<1024, 256, 0, stream>>>(xb, W0b, b0, Zb, 800, 1024);
    act_kernel<<<8192, 256, 0, stream>>>(Zb, mask1, tids, hb, mo1);
    gemm_bt<<<1024, 256, 0, stream>>>(hb, W1b, b1, Zb, 1024, 1024);
    act_kernel<<<8192, 256, 0, stream>>>(Zb, mask2, tids + 1024, hb, mo2);
    gemm_bt<<<1024, 256, 0, stream>>>(hb, W2b, b2, Zb, 1024, 1024);
    act_final<<<8192, 256, 0, stream>>>(Zb, mask3, tids + 2048, W3b, b3, mo3, out);
}